// Round 9
// baseline (292.853 us; speedup 1.0000x reference)
//
#include <hip/hip_runtime.h>
#include <hip/hip_bf16.h>

typedef float nt4 __attribute__((ext_vector_type(4)));

constexpr int Bc  = 2;
constexpr int Nc  = 256;
constexpr int Dc  = 256;
constexpr int DHc = 256;

// 16-lane sum via DPP (VALU-only): quad_perm[1,0,3,2], quad_perm[2,3,0,1],
// row_half_mirror, row_mirror. All 16 lanes end with the group sum.
__device__ __forceinline__ float dpp_sum16(float v) {
    float t;
    t = __int_as_float(__builtin_amdgcn_mov_dpp(__float_as_int(v), 0xB1, 0xF, 0xF, true)); v += t;
    t = __int_as_float(__builtin_amdgcn_mov_dpp(__float_as_int(v), 0x4E, 0xF, 0xF, true)); v += t;
    t = __int_as_float(__builtin_amdgcn_mov_dpp(__float_as_int(v), 0x141, 0xF, 0xF, true)); v += t;
    t = __int_as_float(__builtin_amdgcn_mov_dpp(__float_as_int(v), 0x140, 0xF, 0xF, true)); v += t;
    return v;
}

// ---- prep: K,V = x@W + b;  G = scale*K@Wq^T;  cc = scale*<bq,K_row>; also x->out ----
__global__ __launch_bounds__(256)
void prep_gvc(const float* __restrict__ x,
              const float* __restrict__ Wq, const float* __restrict__ bq,
              const float* __restrict__ Wk, const float* __restrict__ bk,
              const float* __restrict__ Wv, const float* __restrict__ bv,
              float* __restrict__ G, float* __restrict__ V, float* __restrict__ cc,
              float* __restrict__ xout) {
    constexpr int RPB = 4;
    constexpr float scale = 0.0625f;    // 1/sqrt(DH)
    __shared__ float xs[RPB][Dc];
    __shared__ float ks[RPB][DHc];
    const int r0 = blockIdx.x * RPB;
    const int dd = threadIdx.x;

    #pragma unroll
    for (int rr = 0; rr < RPB; ++rr) {
        float xv = x[(size_t)(r0 + rr) * Dc + dd];
        xs[rr][dd] = xv;
        xout[(size_t)(r0 + rr) * Dc + dd] = xv;   // passthrough output 0
    }
    __syncthreads();

    float ka[RPB], va[RPB];
    {
        float bkv = bk[dd], bvv = bv[dd];
        #pragma unroll
        for (int rr = 0; rr < RPB; ++rr) { ka[rr] = bkv; va[rr] = bvv; }
    }
    #pragma unroll 4
    for (int d0 = 0; d0 < Dc; ++d0) {
        float wk = Wk[(size_t)d0 * DHc + dd];
        float wv = Wv[(size_t)d0 * DHc + dd];
        #pragma unroll
        for (int rr = 0; rr < RPB; ++rr) {
            ka[rr] += xs[rr][d0] * wk;
            va[rr] += xs[rr][d0] * wv;
        }
    }
    #pragma unroll
    for (int rr = 0; rr < RPB; ++rr) {
        ks[rr][dd] = ka[rr];
        V[(size_t)(r0 + rr) * DHc + dd] = va[rr];
    }
    __syncthreads();

    float ga[RPB] = {};
    #pragma unroll 8
    for (int h = 0; h < DHc; ++h) {
        float wq = Wq[(size_t)dd * DHc + h];
        #pragma unroll
        for (int rr = 0; rr < RPB; ++rr) ga[rr] += ks[rr][h] * wq;
    }
    #pragma unroll
    for (int rr = 0; rr < RPB; ++rr)
        G[(size_t)(r0 + rr) * Dc + dd] = ga[rr] * scale;

    {
        int rr = dd >> 6, l = dd & 63;
        float p = 0.f;
        #pragma unroll
        for (int k = 0; k < 4; ++k) p += ks[rr][l + 64 * k] * bq[l + 64 * k];
        #pragma unroll
        for (int m = 1; m < 64; m <<= 1) p += __shfl_xor(p, m, 64);
        if (l == 0) cc[r0 + rr] = p * scale;
    }
}

// ---- fused edge pass, explicit ILP-2 per 16-lane group ----
// wave -> (b, j, 16-row segment). Group g (16 lanes) owns rows u*8+g*2+{0,1}
// per super-iter u=0,1. All e/G loads of a super-iter issue before any use;
// the two rows' dot->DPP16->exp->combine chains interleave in-lane.
__global__ __launch_bounds__(256)
void edge_fused(const float* __restrict__ e,
                const float* __restrict__ G,
                const float* __restrict__ V,
                const float* __restrict__ cc,
                float* __restrict__ eout) {
    const int W = blockIdx.x * 4 + (threadIdx.x >> 6);   // 0..8191
    const int l = threadIdx.x & 63;
    const int b   = W >> 12;
    const int rem = W & 4095;
    const int j   = rem >> 4;
    const int seg = rem & 15;
    const int r0  = seg * 16;
    const int g   = l >> 4;
    const int c4  = l & 15;

    const size_t nb = (size_t)b * Nc;
    const float4* G4 = reinterpret_cast<const float4*>(G);
    const float4* V4 = reinterpret_cast<const float4*>(V);

    float4 gj[4], vj[4];
    #pragma unroll
    for (int k = 0; k < 4; ++k) {
        gj[k] = G4[(nb + j) * 64 + c4 + 16 * k];
        vj[k] = V4[(nb + j) * 64 + c4 + 16 * k];
    }
    const float cj = cc[nb + j];

    const float4* e4  = reinterpret_cast<const float4*>(e) +
                        (((size_t)b * Nc + j) * Nc + r0) * 64;
    float4* o4 = reinterpret_cast<float4*>(eout) +
                 (((size_t)b * Nc + j) * Nc + r0) * 64;
    const float4* Gi  = G4 + (nb + r0) * 64;
    const float4* Vi  = V4 + (nb + r0) * 64;
    const float*  ccp = cc + nb + r0;

    #pragma unroll
    for (int u = 0; u < 2; ++u) {
        const int rA = u * 8 + g * 2;
        const int rB = rA + 1;

        // --- issue all e + G loads for both rows up front ---
        float4 evA[4], evB[4], giA[4], giB[4];
        #pragma unroll
        for (int k = 0; k < 4; ++k) evA[k] = e4[(size_t)rA * 64 + c4 + 16 * k];
        #pragma unroll
        for (int k = 0; k < 4; ++k) evB[k] = e4[(size_t)rB * 64 + c4 + 16 * k];
        #pragma unroll
        for (int k = 0; k < 4; ++k) giA[k] = Gi[(size_t)rA * 64 + c4 + 16 * k];
        #pragma unroll
        for (int k = 0; k < 4; ++k) giB[k] = Gi[(size_t)rB * 64 + c4 + 16 * k];
        const float ciA = ccp[rA];
        const float ciB = ccp[rB];

        // --- two independent dot chains ---
        float siA = 0.f, sjA = 0.f, siB = 0.f, sjB = 0.f;
        #pragma unroll
        for (int k = 0; k < 4; ++k) {
            siA += evA[k].x * giA[k].x + evA[k].y * giA[k].y +
                   evA[k].z * giA[k].z + evA[k].w * giA[k].w;
            siB += evB[k].x * giB[k].x + evB[k].y * giB[k].y +
                   evB[k].z * giB[k].z + evB[k].w * giB[k].w;
            sjA += evA[k].x * gj[k].x + evA[k].y * gj[k].y +
                   evA[k].z * gj[k].z + evA[k].w * gj[k].w;
            sjB += evB[k].x * gj[k].x + evB[k].y * gj[k].y +
                   evB[k].z * gj[k].z + evB[k].w * gj[k].w;
        }

        // --- 4 interleaved DPP reduce chains ---
        siA = dpp_sum16(siA); sjA = dpp_sum16(sjA);
        siB = dpp_sum16(siB); sjB = dpp_sum16(sjB);
        siA += ciA; sjA += cj;
        siB += ciB; sjB += cj;
        const float aiA = 1.f / (1.f + __expf(sjA - siA));  // pre-scaled by 1/16
        const float aiB = 1.f / (1.f + __expf(sjB - siB));
        const float ajA = 1.f - aiA;
        const float ajB = 1.f - aiB;

        // --- V loads (off the reduce chain) + combine + NT store ---
        float4 viA[4], viB[4];
        #pragma unroll
        for (int k = 0; k < 4; ++k) viA[k] = Vi[(size_t)rA * 64 + c4 + 16 * k];
        #pragma unroll
        for (int k = 0; k < 4; ++k) viB[k] = Vi[(size_t)rB * 64 + c4 + 16 * k];

        #pragma unroll
        for (int k = 0; k < 4; ++k) {
            nt4 oA, oB;
            oA.x = aiA * viA[k].x + ajA * vj[k].x;
            oA.y = aiA * viA[k].y + ajA * vj[k].y;
            oA.z = aiA * viA[k].z + ajA * vj[k].z;
            oA.w = aiA * viA[k].w + ajA * vj[k].w;
            oB.x = aiB * viB[k].x + ajB * vj[k].x;
            oB.y = aiB * viB[k].y + ajB * vj[k].y;
            oB.z = aiB * viB[k].z + ajB * vj[k].z;
            oB.w = aiB * viB[k].w + ajB * vj[k].w;
            __builtin_nontemporal_store(
                oA, reinterpret_cast<nt4*>(&o4[(size_t)rA * 64 + c4 + 16 * k]));
            __builtin_nontemporal_store(
                oB, reinterpret_cast<nt4*>(&o4[(size_t)rB * 64 + c4 + 16 * k]));
        }
    }
}

extern "C" void kernel_launch(void* const* d_in, const int* in_sizes, int n_in,
                              void* d_out, int out_size, void* d_ws, size_t ws_size,
                              hipStream_t stream) {
    const float* x  = (const float*)d_in[0];
    const float* e  = (const float*)d_in[1];
    const float* Wq = (const float*)d_in[2];
    const float* bq = (const float*)d_in[3];
    const float* Wk = (const float*)d_in[4];
    const float* bk = (const float*)d_in[5];
    const float* Wv = (const float*)d_in[6];
    const float* bv = (const float*)d_in[7];
    float* out = (float*)d_out;

    float* G  = (float*)d_ws;                        // [B*N, D]
    float* V  = G + (size_t)Bc * Nc * Dc;            // [B*N, DH]
    float* cc = V + (size_t)Bc * Nc * DHc;           // [B*N]

    float* eo = out + (size_t)Bc * Nc * Dc;

    prep_gvc<<<Bc * Nc / 4, 256, 0, stream>>>(x, Wq, bq, Wk, bk, Wv, bv,
                                              G, V, cc, out);
    edge_fused<<<Bc * Nc * 16 / 4, 256, 0, stream>>>(e, G, V, cc, eo);
}